// Round 1
// baseline (527.640 us; speedup 1.0000x reference)
//
#include <hip/hip_runtime.h>
#include <cstdint>
#include <cstddef>

typedef unsigned short u16;
typedef unsigned int u32;
typedef __attribute__((ext_vector_type(4))) float f32x4;
typedef __attribute__((ext_vector_type(8))) short s16x8;

__device__ __forceinline__ u16 f2bf(float f) {
  u32 u = __float_as_uint(f);
  u = (u + 0x7fffu + ((u >> 16) & 1u)) >> 16;
  return (u16)u;
}

__device__ __forceinline__ float silu_f(float y) {
  return y / (1.0f + __expf(-y));
}

// ---------------------------------------------------------------------------
// Weight quantization: one block per output channel.
// Exact median of |w| via binary search on float bit pattern (monotone for
// non-negative floats). Writes ternary {-1,0,+1} bf16 weights and fused
// BN coefficients alpha/beta.
// ---------------------------------------------------------------------------
template<int N, int REMAP>
__global__ __launch_bounds__(256) void quant_kernel(
    const float* __restrict__ w, const float* __restrict__ bias,
    const float* __restrict__ g, const float* __restrict__ be,
    const float* __restrict__ mu, const float* __restrict__ var,
    u16* __restrict__ wq, float* __restrict__ alpha, float* __restrict__ beta)
{
  __shared__ u32 au[N];
  __shared__ int cnt;
  const int ch = blockIdx.x;
  const int tid = threadIdx.x;
  const float* wp = w + (size_t)ch * N;
  for (int i = tid; i < N; i += 256) au[i] = __float_as_uint(fabsf(wp[i]));
  __syncthreads();

  u32 res[2];
  #pragma unroll
  for (int t = 0; t < 2; ++t) {
    const int k = N / 2 - 1 + t;  // 0-indexed rank
    u32 lo = 0u, hi = 0xFFFFFFFFu;
    while (lo < hi) {
      u32 mid = lo + ((hi - lo) >> 1);
      if (tid == 0) cnt = 0;
      __syncthreads();
      int c = 0;
      for (int i = tid; i < N; i += 256) c += (au[i] <= mid) ? 1 : 0;
      if (c) atomicAdd(&cnt, c);
      __syncthreads();
      int total = cnt;
      __syncthreads();
      if (total >= k + 1) hi = mid; else lo = mid + 1;
    }
    res[t] = lo;
  }
  float s = 0.5f * (__uint_as_float(res[0]) + __uint_as_float(res[1]));
  s = fmaxf(s, 1e-8f);

  for (int i = tid; i < N; i += 256) {
    float q = rintf(wp[i] / s);            // matches jnp.round (RNE)
    q = fminf(fmaxf(q, -1.0f), 1.0f);
    int oi;
    if (REMAP) {                            // OIHW [cin][3][3] -> k = tap*256 + cin
      int cin = i / 9, tap = i - cin * 9;
      oi = tap * 256 + cin;
    } else {
      oi = i;
    }
    wq[(size_t)ch * N + oi] = f2bf(q);
  }
  if (tid == 0) {
    float sc = g[ch] / sqrtf(var[ch] + 1e-5f);
    alpha[ch] = s * sc;
    beta[ch] = (bias[ch] - mu[ch]) * sc + be[ch];
  }
}

// ---------------------------------------------------------------------------
// x (NCHW fp32) -> xb (NHWC bf16): [64][196][1024]
// ---------------------------------------------------------------------------
__global__ __launch_bounds__(256) void transpose_cast_kernel(
    const float* __restrict__ x, u16* __restrict__ xb)
{
  __shared__ u16 tile[64 * 196];
  const int n = blockIdx.x;
  const int c0 = blockIdx.y * 64;
  const float* xp = x + ((size_t)n * 1024 + c0) * 196;
  for (int i = threadIdx.x; i < 64 * 196; i += 256)
    tile[i] = f2bf(xp[i]);                  // coalesced read along hw
  __syncthreads();
  u16* op = xb + (size_t)n * 196 * 1024 + c0;
  for (int i = threadIdx.x; i < 64 * 196; i += 256) {
    int hw = i >> 6, c = i & 63;
    op[(size_t)hw * 1024 + c] = tile[c * 196 + hw];  // coalesced write along c
  }
}

// ---------------------------------------------------------------------------
// GEMM: C[c][j] = sum_k W[c][k] * Act[j][k], 128x128 tile, BK=64,
// mfma_f32_16x16x32_bf16, both operands K-major, XOR-swizzled LDS.
// MODE 1: B = xb flat [j][1024]; store silu(bn) bf16 into padded act1p
// MODE 2: B gathered from act1p (implicit 3x3); store silu(bn) bf16 flat act2
// MODE 3: B = act2 flat [j][256]; store silu(bn + x) fp32 NCHW
// ---------------------------------------------------------------------------
template<int MODE, int KTOT>
__global__ __launch_bounds__(256, 2) void gemm_kernel(
    const u16* __restrict__ Wq, const u16* __restrict__ Bact,
    const float* __restrict__ alpha, const float* __restrict__ beta,
    u16* __restrict__ outb, float* __restrict__ outf, const float* __restrict__ xres)
{
  constexpr int BK = 64;
  constexpr int NKT = KTOT / BK;
  __shared__ u16 As[128 * BK];
  __shared__ u16 Bs[128 * BK];
  __shared__ int rowbase[128];
  __shared__ float aS[128], bS[128];

  const int tid = threadIdx.x;
  const int jb = blockIdx.x * 128;   // j (position) tile
  const int cb = blockIdx.y * 128;   // output-channel tile
  const int wave = tid >> 6;
  const int lane = tid & 63;
  const int wm = (wave & 1) * 64;
  const int wn = (wave >> 1) * 64;
  const int quad = lane >> 4;
  const int l16 = lane & 15;

  if (tid < 128) {
    aS[tid] = alpha[cb + tid];
    bS[tid] = beta[cb + tid];
    if (MODE == 2) {
      int j = jb + tid;
      int n = j / 196, hw = j - n * 196;
      int h = hw / 14, w = hw - h * 14;
      rowbase[tid] = ((n * 16 + h) * 16 + w) * 256;  // padded NHWC base, tap (0,0)
    }
  }
  __syncthreads();

  f32x4 acc[4][4];
  #pragma unroll
  for (int a = 0; a < 4; ++a)
    #pragma unroll
    for (int b = 0; b < 4; ++b)
      acc[a][b] = {0.f, 0.f, 0.f, 0.f};

  const int row_s = tid >> 3;   // staging row (0..31), +32*i
  const int cc_s = tid & 7;     // 16B chunk within BK row

  for (int kt = 0; kt < NKT; ++kt) {
    {   // stage A (weights), coalesced 16B loads, swizzled LDS write
      const uint4* gp = reinterpret_cast<const uint4*>(Wq + (size_t)cb * KTOT + kt * BK);
      #pragma unroll
      for (int i = 0; i < 4; ++i) {
        int row = row_s + 32 * i;
        uint4 v = gp[(size_t)row * (KTOT / 8) + cc_s];
        *reinterpret_cast<uint4*>(&As[row * BK + ((cc_s ^ (row & 7)) << 3)]) = v;
      }
    }
    if (MODE == 2) {   // implicit 3x3 gather: tap = kt/4, cin chunk = (kt%4)*64
      int tap = kt >> 2;
      int c0 = (kt & 3) * 64;
      int dy = tap / 3, dx = tap - dy * 3;
      int tapoff = (dy * 16 + dx) * 256 + c0;
      const uint4* gp = reinterpret_cast<const uint4*>(Bact);
      #pragma unroll
      for (int i = 0; i < 4; ++i) {
        int row = row_s + 32 * i;
        uint4 v = gp[((rowbase[row] + tapoff) >> 3) + cc_s];
        *reinterpret_cast<uint4*>(&Bs[row * BK + ((cc_s ^ (row & 7)) << 3)]) = v;
      }
    } else {
      const uint4* gp = reinterpret_cast<const uint4*>(Bact + (size_t)jb * KTOT + kt * BK);
      #pragma unroll
      for (int i = 0; i < 4; ++i) {
        int row = row_s + 32 * i;
        uint4 v = gp[(size_t)row * (KTOT / 8) + cc_s];
        *reinterpret_cast<uint4*>(&Bs[row * BK + ((cc_s ^ (row & 7)) << 3)]) = v;
      }
    }
    __syncthreads();

    #pragma unroll
    for (int s = 0; s < 2; ++s) {
      s16x8 af[4], bf[4];
      #pragma unroll
      for (int mi = 0; mi < 4; ++mi) {
        int row = wm + mi * 16 + l16;
        int kc = s * 4 + quad;
        af[mi] = *reinterpret_cast<const s16x8*>(&As[row * BK + ((kc ^ (row & 7)) << 3)]);
      }
      #pragma unroll
      for (int ni = 0; ni < 4; ++ni) {
        int row = wn + ni * 16 + l16;
        int kc = s * 4 + quad;
        bf[ni] = *reinterpret_cast<const s16x8*>(&Bs[row * BK + ((kc ^ (row & 7)) << 3)]);
      }
      #pragma unroll
      for (int mi = 0; mi < 4; ++mi)
        #pragma unroll
        for (int ni = 0; ni < 4; ++ni)
          acc[mi][ni] = __builtin_amdgcn_mfma_f32_16x16x32_bf16(af[mi], bf[ni], acc[mi][ni], 0, 0, 0);
    }
    __syncthreads();
  }

  // Epilogue. D layout: row(channel) = quad*4 + reg, col(j) = lane&15.
  #pragma unroll
  for (int mi = 0; mi < 4; ++mi) {
    const int lc = wm + mi * 16 + quad * 4;   // local channel base of the 4 regs
    #pragma unroll
    for (int ni = 0; ni < 4; ++ni) {
      const int j = jb + wn + ni * 16 + l16;
      if (MODE == 1) {
        int n = j / 196, hw = j - n * 196;
        int h = hw / 14, w = hw - h * 14;
        size_t base = (size_t)(((n * 16 + h + 1) * 16) + (w + 1)) * 256 + cb + lc;
        ushort4 pk;
        float y;
        y = silu_f(aS[lc + 0] * acc[mi][ni][0] + bS[lc + 0]); pk.x = f2bf(y);
        y = silu_f(aS[lc + 1] * acc[mi][ni][1] + bS[lc + 1]); pk.y = f2bf(y);
        y = silu_f(aS[lc + 2] * acc[mi][ni][2] + bS[lc + 2]); pk.z = f2bf(y);
        y = silu_f(aS[lc + 3] * acc[mi][ni][3] + bS[lc + 3]); pk.w = f2bf(y);
        *reinterpret_cast<ushort4*>(&outb[base]) = pk;
      } else if (MODE == 2) {
        size_t base = (size_t)j * 256 + cb + lc;
        ushort4 pk;
        float y;
        y = silu_f(aS[lc + 0] * acc[mi][ni][0] + bS[lc + 0]); pk.x = f2bf(y);
        y = silu_f(aS[lc + 1] * acc[mi][ni][1] + bS[lc + 1]); pk.y = f2bf(y);
        y = silu_f(aS[lc + 2] * acc[mi][ni][2] + bS[lc + 2]); pk.z = f2bf(y);
        y = silu_f(aS[lc + 3] * acc[mi][ni][3] + bS[lc + 3]); pk.w = f2bf(y);
        *reinterpret_cast<ushort4*>(&outb[base]) = pk;
      } else {
        int n = j / 196, hw = j - n * 196;
        #pragma unroll
        for (int r = 0; r < 4; ++r) {
          int c = cb + lc + r;
          size_t idx = (size_t)n * 200704 + (size_t)c * 196 + hw;
          float y = aS[lc + r] * acc[mi][ni][r] + bS[lc + r] + xres[idx];
          outf[idx] = silu_f(y);
        }
      }
    }
  }
}

// ---------------------------------------------------------------------------
extern "C" void kernel_launch(void* const* d_in, const int* in_sizes, int n_in,
                              void* d_out, int out_size, void* d_ws, size_t ws_size,
                              hipStream_t stream)
{
  const float* x   = (const float*)d_in[0];
  const float* w1  = (const float*)d_in[1];
  const float* b1  = (const float*)d_in[2];
  const float* g1  = (const float*)d_in[3];
  const float* be1 = (const float*)d_in[4];
  const float* m1  = (const float*)d_in[5];
  const float* v1  = (const float*)d_in[6];
  const float* w2  = (const float*)d_in[7];
  const float* b2  = (const float*)d_in[8];
  const float* g2  = (const float*)d_in[9];
  const float* be2 = (const float*)d_in[10];
  const float* m2  = (const float*)d_in[11];
  const float* v2  = (const float*)d_in[12];
  const float* w3  = (const float*)d_in[13];
  const float* b3  = (const float*)d_in[14];
  const float* g3  = (const float*)d_in[15];
  const float* be3 = (const float*)d_in[16];
  const float* m3  = (const float*)d_in[17];
  const float* v3  = (const float*)d_in[18];
  float* out = (float*)d_out;

  uint8_t* ws = (uint8_t*)d_ws;
  u16* xb    = (u16*)(ws);                      // 12544*1024*2 = 25,690,112 B
  u16* act1p = (u16*)(ws + 25690112ull);        // 64*16*16*256*2 = 8,388,608 B
  u16* act2  = (u16*)(ws + 34078720ull);        // 12544*256*2 = 6,422,528 B
  u16* w1q   = (u16*)(ws + 40501248ull);        // 256*1024*2 = 524,288 B
  u16* w2q   = (u16*)(ws + 41025536ull);        // 256*2304*2 = 1,179,648 B
  u16* w3q   = (u16*)(ws + 42205184ull);        // 1024*256*2 = 524,288 B
  float* a1c = (float*)(ws + 42729472ull);
  float* b1c = a1c + 256;
  float* a2c = b1c + 256;
  float* b2c = a2c + 256;
  float* a3c = b2c + 256;
  float* b3c = a3c + 1024;

  hipMemsetAsync(act1p, 0, 8388608ull, stream);  // zero borders of padded act1

  transpose_cast_kernel<<<dim3(64, 16), 256, 0, stream>>>(x, xb);
  quant_kernel<1024, 0><<<256, 256, 0, stream>>>(w1, b1, g1, be1, m1, v1, w1q, a1c, b1c);
  quant_kernel<2304, 1><<<256, 256, 0, stream>>>(w2, b2, g2, be2, m2, v2, w2q, a2c, b2c);
  quant_kernel<256, 0><<<1024, 256, 0, stream>>>(w3, b3, g3, be3, m3, v3, w3q, a3c, b3c);

  gemm_kernel<1, 1024><<<dim3(98, 2), 256, 0, stream>>>(w1q, xb, a1c, b1c, act1p, (float*)nullptr, (const float*)nullptr);
  gemm_kernel<2, 2304><<<dim3(98, 2), 256, 0, stream>>>(w2q, act1p, a2c, b2c, act2, (float*)nullptr, (const float*)nullptr);
  gemm_kernel<3, 256><<<dim3(98, 8), 256, 0, stream>>>(w3q, act2, a3c, b3c, (u16*)nullptr, out, x);
}

// Round 2
// 279.769 us; speedup vs baseline: 1.8860x; 1.8860x over previous
//
#include <hip/hip_runtime.h>
#include <cstdint>
#include <cstddef>

typedef unsigned short u16;
typedef unsigned int u32;
typedef __attribute__((ext_vector_type(4))) float f32x4;
typedef __attribute__((ext_vector_type(8))) short s16x8;

__device__ __forceinline__ u16 f2bf(float f) {
  u32 u = __float_as_uint(f);
  u = (u + 0x7fffu + ((u >> 16) & 1u)) >> 16;
  return (u16)u;
}

__device__ __forceinline__ float silu_f(float y) {
  return y / (1.0f + __expf(-y));
}

// ---------------------------------------------------------------------------
// Weight quantization: ONE WAVE per output channel, 4 channels per block.
// Exact median of |w| via 8-bit radix select (4 passes) on the abs bit
// pattern (monotone for non-negative floats), + 1 cleanup pass for the
// second middle order statistic. No per-iteration block barriers.
// Writes ternary {-1,0,+1} bf16 weights and fused BN coefficients.
// ---------------------------------------------------------------------------
template<int N, int REMAP>
__global__ __launch_bounds__(256) void quant_kernel(
    const float* __restrict__ w, const float* __restrict__ bias,
    const float* __restrict__ g, const float* __restrict__ be,
    const float* __restrict__ mu, const float* __restrict__ var,
    u16* __restrict__ wq, float* __restrict__ alpha, float* __restrict__ beta)
{
  constexpr int NV = N / 64;           // values per lane (N divisible by 64)
  __shared__ int hist[4 * 256];        // one 256-bin histogram per wave

  const int tid = threadIdx.x;
  const int wave = tid >> 6;
  const int lane = tid & 63;
  const int ch = blockIdx.x * 4 + wave;
  const int wb = wave * 256;

  // Load raw bits (keep sign; mask to abs on use). Coalesced 4B loads.
  u32 vals[NV];
  const float* wp = w + (size_t)ch * N;
  #pragma unroll
  for (int t = 0; t < NV; ++t)
    vals[t] = __float_as_uint(wp[lane + 64 * t]);

  // --- radix select: find v0 = (N/2)-th smallest (1-indexed) of abs bits ---
  const int r0 = N / 2;
  int r = r0;
  u32 prefix = 0;
  #pragma unroll
  for (int pass = 0; pass < 4; ++pass) {
    const int shift = 24 - 8 * pass;
    // zero this wave's histogram
    hist[wb + lane] = 0;
    hist[wb + 64 + lane] = 0;
    hist[wb + 128 + lane] = 0;
    hist[wb + 192 + lane] = 0;
    __syncthreads();
    #pragma unroll
    for (int t = 0; t < NV; ++t) {
      u32 a = vals[t] & 0x7fffffffu;
      bool cand;
      if (pass == 0) cand = true;
      else cand = ((a >> (shift + 8)) == (prefix >> (shift + 8)));
      if (cand) atomicAdd(&hist[wb + ((a >> shift) & 255)], 1);
    }
    __syncthreads();
    // lane owns bins 4*lane .. 4*lane+3
    int h0 = hist[wb + 4 * lane + 0];
    int h1 = hist[wb + 4 * lane + 1];
    int h2 = hist[wb + 4 * lane + 2];
    int h3 = hist[wb + 4 * lane + 3];
    int s4 = h0 + h1 + h2 + h3;
    int cum = s4;
    #pragma unroll
    for (int off = 1; off < 64; off <<= 1) {
      int tt = __shfl_up(cum, off);
      if (lane >= off) cum += tt;
    }
    int pre = cum - s4;
    bool sel = (r > pre) && (r <= cum);
    unsigned long long bal = __ballot(sel);
    int src = __ffsll((unsigned long long)bal) - 1;
    // local digit walk (valid on the selected lane)
    int c0 = pre + h0, c1 = c0 + h1, c2 = c1 + h2;
    int d_l, nr_l;
    if (r <= c0)      { d_l = 4 * lane + 0; nr_l = r - pre; }
    else if (r <= c1) { d_l = 4 * lane + 1; nr_l = r - c0; }
    else if (r <= c2) { d_l = 4 * lane + 2; nr_l = r - c1; }
    else              { d_l = 4 * lane + 3; nr_l = r - c2; }
    int d = __shfl(d_l, src);
    r = __shfl(nr_l, src);
    prefix |= (u32)d << shift;
    __syncthreads();
  }
  const u32 v0 = prefix;

  // --- second middle element: rank r0+1 ---
  int cle = 0;
  u32 mn = 0xFFFFFFFFu;
  #pragma unroll
  for (int t = 0; t < NV; ++t) {
    u32 a = vals[t] & 0x7fffffffu;
    cle += (a <= v0) ? 1 : 0;
    if (a > v0) mn = min(mn, a);
  }
  #pragma unroll
  for (int off = 1; off < 64; off <<= 1) {
    cle += __shfl_xor(cle, off);
    mn = min(mn, (u32)__shfl_xor((int)mn, off));
  }
  u32 v1 = (cle >= r0 + 1) ? v0 : mn;

  float s = 0.5f * (__uint_as_float(v0) + __uint_as_float(v1));
  s = fmaxf(s, 1e-8f);

  // --- quantize + write ternary bf16 weights ---
  #pragma unroll
  for (int t = 0; t < NV; ++t) {
    int i = lane + 64 * t;
    float q = rintf(__uint_as_float(vals[t]) / s);   // RNE, matches jnp.round
    q = fminf(fmaxf(q, -1.0f), 1.0f);
    int oi;
    if (REMAP) {                       // OIHW [cin][3][3] -> k = tap*256 + cin
      int cin = i / 9, tap = i - cin * 9;
      oi = tap * 256 + cin;
    } else {
      oi = i;
    }
    wq[(size_t)ch * N + oi] = f2bf(q);
  }
  if (lane == 0) {
    float sc = g[ch] / sqrtf(var[ch] + 1e-5f);
    alpha[ch] = s * sc;
    beta[ch] = (bias[ch] - mu[ch]) * sc + be[ch];
  }
}

// ---------------------------------------------------------------------------
// x (NCHW fp32) -> xb (NHWC bf16): [64][196][1024]
// LDS tile padded to stride 198 (u16): read bank-stride = 99 dwords == 3 mod
// 32 -> conflict-free (2-way aliasing only).
// ---------------------------------------------------------------------------
__global__ __launch_bounds__(256) void transpose_cast_kernel(
    const float* __restrict__ x, u16* __restrict__ xb)
{
  __shared__ u16 tile[64 * 198];
  const int n = blockIdx.x;
  const int c0 = blockIdx.y * 64;
  const float* xp = x + ((size_t)n * 1024 + c0) * 196;
  for (int i = threadIdx.x; i < 64 * 196; i += 256) {
    int c = i / 196, hw = i - c * 196;
    tile[c * 198 + hw] = f2bf(xp[i]);        // coalesced read along hw
  }
  __syncthreads();
  u16* op = xb + (size_t)n * 196 * 1024 + c0;
  for (int i = threadIdx.x; i < 64 * 196; i += 256) {
    int hw = i >> 6, c = i & 63;
    op[(size_t)hw * 1024 + c] = tile[c * 198 + hw];  // coalesced write along c
  }
}

// ---------------------------------------------------------------------------
// GEMM: C[c][j] = sum_k W[c][k] * Act[j][k], 128x128 tile, BK=64,
// mfma_f32_16x16x32_bf16, both operands K-major, XOR-swizzled LDS.
// MODE 1: B = xb flat [j][1024]; store silu(bn) bf16 into padded act1p
// MODE 2: B gathered from act1p (implicit 3x3); store silu(bn) bf16 flat act2
// MODE 3: B = act2 flat [j][256]; store silu(bn + x) fp32 NCHW
// ---------------------------------------------------------------------------
template<int MODE, int KTOT>
__global__ __launch_bounds__(256, 2) void gemm_kernel(
    const u16* __restrict__ Wq, const u16* __restrict__ Bact,
    const float* __restrict__ alpha, const float* __restrict__ beta,
    u16* __restrict__ outb, float* __restrict__ outf, const float* __restrict__ xres)
{
  constexpr int BK = 64;
  constexpr int NKT = KTOT / BK;
  __shared__ u16 As[128 * BK];
  __shared__ u16 Bs[128 * BK];
  __shared__ int rowbase[128];
  __shared__ float aS[128], bS[128];

  const int tid = threadIdx.x;
  const int jb = blockIdx.x * 128;   // j (position) tile
  const int cb = blockIdx.y * 128;   // output-channel tile
  const int wave = tid >> 6;
  const int lane = tid & 63;
  const int wm = (wave & 1) * 64;
  const int wn = (wave >> 1) * 64;
  const int quad = lane >> 4;
  const int l16 = lane & 15;

  if (tid < 128) {
    aS[tid] = alpha[cb + tid];
    bS[tid] = beta[cb + tid];
    if (MODE == 2) {
      int j = jb + tid;
      int n = j / 196, hw = j - n * 196;
      int h = hw / 14, w = hw - h * 14;
      rowbase[tid] = ((n * 16 + h) * 16 + w) * 256;  // padded NHWC base, tap (0,0)
    }
  }
  __syncthreads();

  f32x4 acc[4][4];
  #pragma unroll
  for (int a = 0; a < 4; ++a)
    #pragma unroll
    for (int b = 0; b < 4; ++b)
      acc[a][b] = {0.f, 0.f, 0.f, 0.f};

  const int row_s = tid >> 3;   // staging row (0..31), +32*i
  const int cc_s = tid & 7;     // 16B chunk within BK row

  for (int kt = 0; kt < NKT; ++kt) {
    {   // stage A (weights), coalesced 16B loads, swizzled LDS write
      const uint4* gp = reinterpret_cast<const uint4*>(Wq + (size_t)cb * KTOT + kt * BK);
      #pragma unroll
      for (int i = 0; i < 4; ++i) {
        int row = row_s + 32 * i;
        uint4 v = gp[(size_t)row * (KTOT / 8) + cc_s];
        *reinterpret_cast<uint4*>(&As[row * BK + ((cc_s ^ (row & 7)) << 3)]) = v;
      }
    }
    if (MODE == 2) {   // implicit 3x3 gather: tap = kt/4, cin chunk = (kt%4)*64
      int tap = kt >> 2;
      int c0 = (kt & 3) * 64;
      int dy = tap / 3, dx = tap - dy * 3;
      int tapoff = (dy * 16 + dx) * 256 + c0;
      const uint4* gp = reinterpret_cast<const uint4*>(Bact);
      #pragma unroll
      for (int i = 0; i < 4; ++i) {
        int row = row_s + 32 * i;
        uint4 v = gp[((rowbase[row] + tapoff) >> 3) + cc_s];
        *reinterpret_cast<uint4*>(&Bs[row * BK + ((cc_s ^ (row & 7)) << 3)]) = v;
      }
    } else {
      const uint4* gp = reinterpret_cast<const uint4*>(Bact + (size_t)jb * KTOT + kt * BK);
      #pragma unroll
      for (int i = 0; i < 4; ++i) {
        int row = row_s + 32 * i;
        uint4 v = gp[(size_t)row * (KTOT / 8) + cc_s];
        *reinterpret_cast<uint4*>(&Bs[row * BK + ((cc_s ^ (row & 7)) << 3)]) = v;
      }
    }
    __syncthreads();

    #pragma unroll
    for (int s = 0; s < 2; ++s) {
      s16x8 af[4], bf[4];
      #pragma unroll
      for (int mi = 0; mi < 4; ++mi) {
        int row = wm + mi * 16 + l16;
        int kc = s * 4 + quad;
        af[mi] = *reinterpret_cast<const s16x8*>(&As[row * BK + ((kc ^ (row & 7)) << 3)]);
      }
      #pragma unroll
      for (int ni = 0; ni < 4; ++ni) {
        int row = wn + ni * 16 + l16;
        int kc = s * 4 + quad;
        bf[ni] = *reinterpret_cast<const s16x8*>(&Bs[row * BK + ((kc ^ (row & 7)) << 3)]);
      }
      #pragma unroll
      for (int mi = 0; mi < 4; ++mi)
        #pragma unroll
        for (int ni = 0; ni < 4; ++ni)
          acc[mi][ni] = __builtin_amdgcn_mfma_f32_16x16x32_bf16(af[mi], bf[ni], acc[mi][ni], 0, 0, 0);
    }
    __syncthreads();
  }

  // Epilogue. D layout: row(channel) = quad*4 + reg, col(j) = lane&15.
  #pragma unroll
  for (int mi = 0; mi < 4; ++mi) {
    const int lc = wm + mi * 16 + quad * 4;   // local channel base of the 4 regs
    #pragma unroll
    for (int ni = 0; ni < 4; ++ni) {
      const int j = jb + wn + ni * 16 + l16;
      if (MODE == 1) {
        int n = j / 196, hw = j - n * 196;
        int h = hw / 14, w = hw - h * 14;
        size_t base = (size_t)(((n * 16 + h + 1) * 16) + (w + 1)) * 256 + cb + lc;
        ushort4 pk;
        float y;
        y = silu_f(aS[lc + 0] * acc[mi][ni][0] + bS[lc + 0]); pk.x = f2bf(y);
        y = silu_f(aS[lc + 1] * acc[mi][ni][1] + bS[lc + 1]); pk.y = f2bf(y);
        y = silu_f(aS[lc + 2] * acc[mi][ni][2] + bS[lc + 2]); pk.z = f2bf(y);
        y = silu_f(aS[lc + 3] * acc[mi][ni][3] + bS[lc + 3]); pk.w = f2bf(y);
        *reinterpret_cast<ushort4*>(&outb[base]) = pk;
      } else if (MODE == 2) {
        size_t base = (size_t)j * 256 + cb + lc;
        ushort4 pk;
        float y;
        y = silu_f(aS[lc + 0] * acc[mi][ni][0] + bS[lc + 0]); pk.x = f2bf(y);
        y = silu_f(aS[lc + 1] * acc[mi][ni][1] + bS[lc + 1]); pk.y = f2bf(y);
        y = silu_f(aS[lc + 2] * acc[mi][ni][2] + bS[lc + 2]); pk.z = f2bf(y);
        y = silu_f(aS[lc + 3] * acc[mi][ni][3] + bS[lc + 3]); pk.w = f2bf(y);
        *reinterpret_cast<ushort4*>(&outb[base]) = pk;
      } else {
        int n = j / 196, hw = j - n * 196;
        #pragma unroll
        for (int r = 0; r < 4; ++r) {
          int c = cb + lc + r;
          size_t idx = (size_t)n * 200704 + (size_t)c * 196 + hw;
          float y = aS[lc + r] * acc[mi][ni][r] + bS[lc + r] + xres[idx];
          outf[idx] = silu_f(y);
        }
      }
    }
  }
}

// ---------------------------------------------------------------------------
extern "C" void kernel_launch(void* const* d_in, const int* in_sizes, int n_in,
                              void* d_out, int out_size, void* d_ws, size_t ws_size,
                              hipStream_t stream)
{
  const float* x   = (const float*)d_in[0];
  const float* w1  = (const float*)d_in[1];
  const float* b1  = (const float*)d_in[2];
  const float* g1  = (const float*)d_in[3];
  const float* be1 = (const float*)d_in[4];
  const float* m1  = (const float*)d_in[5];
  const float* v1  = (const float*)d_in[6];
  const float* w2  = (const float*)d_in[7];
  const float* b2  = (const float*)d_in[8];
  const float* g2  = (const float*)d_in[9];
  const float* be2 = (const float*)d_in[10];
  const float* m2  = (const float*)d_in[11];
  const float* v2  = (const float*)d_in[12];
  const float* w3  = (const float*)d_in[13];
  const float* b3  = (const float*)d_in[14];
  const float* g3  = (const float*)d_in[15];
  const float* be3 = (const float*)d_in[16];
  const float* m3  = (const float*)d_in[17];
  const float* v3  = (const float*)d_in[18];
  float* out = (float*)d_out;

  uint8_t* ws = (uint8_t*)d_ws;
  u16* xb    = (u16*)(ws);                      // 12544*1024*2 = 25,690,112 B
  u16* act1p = (u16*)(ws + 25690112ull);        // 64*16*16*256*2 = 8,388,608 B
  u16* act2  = (u16*)(ws + 34078720ull);        // 12544*256*2 = 6,422,528 B
  u16* w1q   = (u16*)(ws + 40501248ull);        // 256*1024*2 = 524,288 B
  u16* w2q   = (u16*)(ws + 41025536ull);        // 256*2304*2 = 1,179,648 B
  u16* w3q   = (u16*)(ws + 42205184ull);        // 1024*256*2 = 524,288 B
  float* a1c = (float*)(ws + 42729472ull);
  float* b1c = a1c + 256;
  float* a2c = b1c + 256;
  float* b2c = a2c + 256;
  float* a3c = b2c + 256;
  float* b3c = a3c + 1024;

  hipMemsetAsync(act1p, 0, 8388608ull, stream);  // zero borders of padded act1

  transpose_cast_kernel<<<dim3(64, 16), 256, 0, stream>>>(x, xb);
  quant_kernel<1024, 0><<<64, 256, 0, stream>>>(w1, b1, g1, be1, m1, v1, w1q, a1c, b1c);
  quant_kernel<2304, 1><<<64, 256, 0, stream>>>(w2, b2, g2, be2, m2, v2, w2q, a2c, b2c);
  quant_kernel<256, 0><<<256, 256, 0, stream>>>(w3, b3, g3, be3, m3, v3, w3q, a3c, b3c);

  gemm_kernel<1, 1024><<<dim3(98, 2), 256, 0, stream>>>(w1q, xb, a1c, b1c, act1p, (float*)nullptr, (const float*)nullptr);
  gemm_kernel<2, 2304><<<dim3(98, 2), 256, 0, stream>>>(w2q, act1p, a2c, b2c, act2, (float*)nullptr, (const float*)nullptr);
  gemm_kernel<3, 256><<<dim3(98, 8), 256, 0, stream>>>(w3q, act2, a3c, b3c, (u16*)nullptr, out, x);
}